// Round 21
// baseline (28.310 us; speedup 1.0000x reference)
//
#include <hip/hip_runtime.h>
#include <math.h>

// DMLoss fused kernel for MI355X (gfx950).
// Round 21: three-pipe split. B-scan constants come from a prep-built global
// table (VMEM, uniform address -> 1 L1 transaction/wave, vmcnt-pipelined);
// C-scan reads ini pairs straight from global (raw input, no prep needed);
// DS pipe keeps only staging + merges. VALU (binder, ~11us/SIMD per R1
// calibration) untouched: scan arithmetic bit-identical to R16 (best 17.9us).
// Pre-committed: >=17.5us -> declare roofline (overlap floor).

#define BB 1024
#define NN 128
#define MM 128

__device__ __forceinline__ float sl1(float x) {
    float d = fabsf(x);
    return d < 1.0f ? 0.5f * d * d : d - 0.5f;
}

// ---------------- prep: fused per-batch segment table (R20, verified) ----------------
__global__ void __launch_bounds__(128)
dmloss_prep(const float* __restrict__ gt, float4* __restrict__ seg)
{
    const int b = blockIdx.x;
    const int m = threadIdx.x;
    __shared__ float2 sg[MM];
    const float2* g2 = (const float2*)(gt + (size_t)b * MM * 2);
    sg[m] = g2[m];
    __syncthreads();
    float2 g = sg[m];
    float2 a = sg[(m + 127) & 127];
    float ex = g.x - a.x, ey = g.y - a.y;
    float A  = ex * ex + ey * ey;
    float inv5 = A > 0.f ? 5.f / A : 0.f;   // degenerate: jv=5, E=0 -> d=Da
    seg[(size_t)b * MM + m] = make_float4(g.x, g.y, inv5, A * 0.01f);
}

// ---------------- main ----------------
__global__ void __launch_bounds__(256, 8)
dmloss_main(const float* __restrict__ ini, const float* __restrict__ pred,
            const float* __restrict__ gt,  const float* __restrict__ kmask,
            const float4* __restrict__ seg, float4* __restrict__ partials)
{
    const int b    = blockIdx.x >> 1;
    const int half = blockIdx.x & 1;      // owns points [64*half, 64*half+64)
    const int tid  = threadIdx.x;
    const int g    = tid & 63;            // owned point: P = 64*half + g
    const int h    = tid >> 6;            // 0..3: scan slice (32 segs / 32 ini)
    const int P    = (half << 6) + g;

    __shared__ __align__(16) float2 s_gt[MM];
    __shared__ float2 s_pr[NN];
    __shared__ float  s_step[16];                // exact j/10
    __shared__ float  s_rv[4 * 64];
    __shared__ float  s_rf[4 * 64];
    __shared__ float  s_sum[3][4];

    const float2* gt2 = (const float2*)(gt   + (size_t)b * MM * 2);
    const float2* in2 = (const float2*)(ini  + (size_t)b * NN * 2);
    const float2* pr2 = (const float2*)(pred + (size_t)b * NN * 2);

    // ---- staging (one barrier): gt + pr in LDS for divergent epilogue gathers ----
    if (tid < 128) {
        s_gt[tid] = gt2[tid];
        if (tid < 16) s_step[tid] = (float)tid / 10.0f;
    } else {
        s_pr[tid - 128] = pr2[tid - 128];
    }
    float2 myP = in2[P];                   // ini_pred point (Phase B owner)
    float2 myG = gt2[P];                   // gt point (Phase C owner)
    const float px = myP.x, py = myP.y;

    // Wave-uniform VMEM scan pointers (all lanes same address -> 1 L1 txn).
    const float4* segg = seg + (size_t)b * MM;                 // B constants
    const float4* inig = (const float4*)(ini + (size_t)b * (NN * 2)); // ini pairs
    __syncthreads();

    float sumA = 0.f, sumB = 0.f, sumC = 0.f;

    // ---- Phase B: rolling-D scan over segs [32h, 32h+32), VMEM constants ----
    // Dg = dist^2(p, gt[m]); jv = (Da-Dg)*inv5 + 5; jr = rint(med3(jv,0,9));
    // d = Da + (E*jr)*(jr - 2*jv); fi = 10*m + jr.  (bit-identical to R16)
    float b0 = INFINITY, f0 = 1e30f;
    {
        const int m0 = 32 * h;
        float4 Sp = segg[(m0 + 127) & 127];           // uniform VMEM load
        float dax = Sp.x - px, day = Sp.y - py;
        float Da = fmaf(day, day, dax * dax);
        float fm = (float)(320 * h);
        #pragma unroll 4
        for (int j = 0; j < 32; ++j) {
            float4 S = segg[m0 + j];                  // global_load_dwordx4 (L1)
            float dgx = S.x - px, dgy = S.y - py;
            float Dg  = fmaf(dgy, dgy, dgx * dgx);
            float jv  = fmaf(Da - Dg, S.z, 5.0f);
            float jr  = rintf(__builtin_amdgcn_fmed3f(jv, 0.f, 9.f));
            float t   = fmaf(jv, -2.f, jr);           // jr - 2*jv
            float d   = fmaf(S.w * jr, t, Da);
            float fi  = fm + jr;
            if (d < b0) { b0 = d; f0 = fi; }          // ascending -> first occ.
            Da = Dg;
            fm += 10.f;
        }
    }
    s_rv[h * 64 + g] = b0;
    s_rf[h * 64 + g] = f0;
    __syncthreads();

    // merge 4 slices (64 active threads) + exact epilogue A
    if (tid < 64) {
        float best = s_rv[tid], bf = s_rf[tid];
        #pragma unroll
        for (int q = 1; q < 4; ++q) {
            float ov = s_rv[q * 64 + tid];
            float of = s_rf[q * 64 + tid];
            if (ov < best || (ov == best && of < bf)) { best = ov; bf = of; }
        }
        int bidx = (int)bf;
        int m = bidx / 10;
        int j = bidx - m * 10;
        float s  = s_step[j];
        float tt = 1.0f - s;
        float2 gm = s_gt[m];
        float2 gp = s_gt[(m + 127) & 127];
        float gx = gm.x * s + gp.x * tt;   // exact reference interp formula
        float gy = gm.y * s + gp.y * tt;
        float2 pr = s_pr[(half << 6) + tid];
        sumA = sl1(pr.x - gx) + sl1(pr.y - gy);
    }
    __syncthreads();   // protect s_rv/s_rf reuse

    // ---- Phase C: owned gt point vs ini slice [32h, 32h+32), VMEM pairs ----
    {
        const float gx = myG.x, gy = myG.y;
        float b1 = INFINITY, f1 = 1e30f;
        float fk = (float)(32 * h);
        const int q0 = 16 * h;            // float4 index: points {2q, 2q+1}
        #pragma unroll 4
        for (int j = 0; j < 16; ++j) {
            float4 I = inig[q0 + j];                  // uniform VMEM load
            {
                float dx = I.x - gx, dy = I.y - gy;
                float d  = fmaf(dy, dy, dx * dx);
                if (d < b1) { b1 = d; f1 = fk; }      // index 2j
            }
            {
                float dx = I.z - gx, dy = I.w - gy;
                float d  = fmaf(dy, dy, dx * dx);
                if (d < b1) { b1 = d; f1 = fk + 1.f; }// index 2j+1 (tie keeps x)
            }
            fk += 2.f;
        }
        s_rv[h * 64 + g] = b1;
        s_rf[h * 64 + g] = f1;
    }
    __syncthreads();

    if (tid < 64) {
        float best = s_rv[tid], bf = s_rf[tid];
        #pragma unroll
        for (int q = 1; q < 4; ++q) {
            float ov = s_rv[q * 64 + tid];
            float of = s_rf[q * 64 + tid];
            if (ov < best || (ov == best && of < bf)) { best = ov; bf = of; }
        }
        int k = (int)bf;
        float2 pk2 = s_pr[k];
        float2 g0  = s_gt[(half << 6) + tid];
        float  km  = kmask[b * MM + (half << 6) + tid];
        sumB = km * (sl1(pk2.x - g0.x) + sl1(pk2.y - g0.y));
        sumC = km;
    }

    // ---- Block reduction ----
    #pragma unroll
    for (int off = 32; off > 0; off >>= 1) {
        sumA += __shfl_down(sumA, off);
        sumB += __shfl_down(sumB, off);
        sumC += __shfl_down(sumC, off);
    }
    const int wave = tid >> 6;
    if ((tid & 63) == 0) {
        s_sum[0][wave] = sumA; s_sum[1][wave] = sumB; s_sum[2][wave] = sumC;
    }
    __syncthreads();
    if (tid == 0) {
        float A = 0.f, Bs = 0.f, C = 0.f;
        #pragma unroll
        for (int w = 0; w < 4; ++w) {
            A += s_sum[0][w]; Bs += s_sum[1][w]; C += s_sum[2][w];
        }
        partials[blockIdx.x] = make_float4(A, Bs, C, 0.0f);
    }
}

__global__ void __launch_bounds__(256)
dmloss_final(const float4* __restrict__ partials, float* __restrict__ out)
{
    const int tid = threadIdx.x;
    float A = 0.0f, Bs = 0.0f, C = 0.0f;
    #pragma unroll
    for (int i = tid; i < 2 * BB; i += 256) {
        float4 p = partials[i];
        A += p.x; Bs += p.y; C += p.z;
    }
    #pragma unroll
    for (int off = 32; off > 0; off >>= 1) {
        A  += __shfl_down(A, off);
        Bs += __shfl_down(Bs, off);
        C  += __shfl_down(C, off);
    }
    __shared__ float sA[4], sB[4], sC[4];
    const int wave = tid >> 6, lane = tid & 63;
    if (lane == 0) { sA[wave] = A; sB[wave] = Bs; sC[wave] = C; }
    __syncthreads();
    if (tid == 0) {
        float a  = sA[0] + sA[1] + sA[2] + sA[3];
        float bs = sB[0] + sB[1] + sB[2] + sB[3];
        float c  = sC[0] + sC[1] + sC[2] + sC[3];
        float loss_pred2gt = a / ((float)BB * (float)NN * 2.0f);
        float loss_set2set = bs / (2.0f * c + 1.0f) + loss_pred2gt;
        out[0] = 0.5f * loss_set2set;
    }
}

extern "C" void kernel_launch(void* const* d_in, const int* in_sizes, int n_in,
                              void* d_out, int out_size, void* d_ws, size_t ws_size,
                              hipStream_t stream)
{
    const float* ini   = (const float*)d_in[0];
    const float* pred  = (const float*)d_in[1];
    const float* gt    = (const float*)d_in[2];
    const float* kmask = (const float*)d_in[3];

    float4* seg      = (float4*)d_ws;                 // 1024*128*16B = 2 MB
    float4* partials = seg + (size_t)BB * MM;         // [2048]

    dmloss_prep<<<dim3(BB), dim3(128), 0, stream>>>(gt, seg);
    dmloss_main<<<dim3(2 * BB), dim3(256), 0, stream>>>(ini, pred, gt, kmask,
                                                        seg, partials);
    dmloss_final<<<dim3(1), dim3(256), 0, stream>>>(partials, (float*)d_out);
}

// Round 22
// 17.831 us; speedup vs baseline: 1.5877x; 1.5877x over previous
//
#include <hip/hip_runtime.h>
#include <math.h>

// DMLoss fused kernel for MI355X (gfx950).  FINAL (= R16, best: 17.9us).
// Two-kernel structure. Phase B: per pred point, argmin over 1280 interp
// points via per-segment convex-quadratic vertex pruning (1 candidate/segment)
// with rolling-D recurrence: Dg = dist^2(p, gt[m]) rolls into the next
// segment's Da, so each candidate needs ONE fused float4 (gx, gy, 5/|e|^2,
// |e|^2/100) LDS broadcast + ~14 VALU. Phase C: direct 128-point argmin.
// 256-thread blocks x 2048 (batch x half), 4-way scan split, LDS-merge,
// exact first-occurrence tie handling, exact reference interp in epilogue.
//
// Measured optimization ladder: naive-fused 57.8 -> vertex-pruning 29.3 ->
// table-free 19.6 -> 256-thr blocks 18.1 -> rolling-D 17.9us. Refuted
// alternatives (all regressed or null): readlane/SGPR constants (38.7),
// pseudo-scalar loads (32.1), atomic-ticket fused tail (+14us), P=2/P=4
// amortization (null), DPP merges (20.9), packed v2f (19.2/21.1), role-split
// blocks (21.8), SMEM constants (24.2), VMEM constants (28.3). LDS broadcast
// is the fastest constant-delivery pipe on CDNA4 for this shape; remaining
// time = ~60%-overlapped dependent VALU+DS issue streams (structural floor).

#define BB 1024
#define NN 128
#define MM 128

__device__ __forceinline__ float sl1(float x) {
    float d = fabsf(x);
    return d < 1.0f ? 0.5f * d * d : d - 0.5f;
}

__global__ void __launch_bounds__(256, 8)
dmloss_main(const float* __restrict__ ini, const float* __restrict__ pred,
            const float* __restrict__ gt,  const float* __restrict__ kmask,
            float4* __restrict__ partials)
{
    const int b    = blockIdx.x >> 1;
    const int half = blockIdx.x & 1;      // owns points [64*half, 64*half+64)
    const int tid  = threadIdx.x;
    const int g    = tid & 63;            // owned point: P = 64*half + g
    const int h    = tid >> 6;            // 0..3: scan slice (32 segs / 32 ini)
    const int P    = (half << 6) + g;

    __shared__ __align__(16) float2 s_gt[MM];
    __shared__ float2 s_pr[NN];
    __shared__ float2 s_ii[NN];
    __shared__ float4 s_seg[MM];                 // (gx, gy, 5/|e|^2, |e|^2/100)
    __shared__ float  s_step[16];                // exact j/10
    __shared__ float  s_rv[4 * 64];
    __shared__ float  s_rf[4 * 64];
    __shared__ float  s_sum[3][4];

    const float2* gt2 = (const float2*)(gt   + (size_t)b * MM * 2);
    const float2* in2 = (const float2*)(ini  + (size_t)b * NN * 2);
    const float2* pr2 = (const float2*)(pred + (size_t)b * NN * 2);

    // ---- staging (one barrier): 256 threads cover 128 segs + 128 pr/ii ----
    if (tid < 128) {
        int m = tid;
        float2 gm = gt2[m];
        float2 a  = gt2[(m + 127) & 127];
        s_gt[m] = gm;
        float ex = gm.x - a.x, ey = gm.y - a.y;
        float A  = ex * ex + ey * ey;
        float inv5 = A > 0.f ? 5.f / A : 0.f;   // degenerate: jv=5, E=0 -> d=Da
        s_seg[m] = make_float4(gm.x, gm.y, inv5, A * 0.01f);
        if (tid < 16) s_step[tid] = (float)tid / 10.0f;
    } else {
        int k = tid - 128;
        s_pr[k] = pr2[k];
        s_ii[k] = in2[k];
    }
    // Own point data (register-resident; coalesced within each wave).
    float2 myP  = in2[P];                  // ini_pred point (Phase B owner)
    float2 myG  = gt2[P];                  // gt point (Phase C owner)
    const float px = myP.x, py = myP.y;
    __syncthreads();

    float sumA = 0.f, sumB = 0.f, sumC = 0.f;

    // ---- Phase B: owned pred point vs segment slice [32h, 32h+32) ----
    // Rolling D: Da = dist^2(p, gt[m-1]); Dg = dist^2(p, gt[m]).
    // jv = (Da-Dg)*inv5 + 5; jr = rint(med3(jv,0,9));
    // d = Da + (E*jr)*(jr - 2*jv); fi = 10*m + jr.
    float b0 = INFINITY, f0 = 1e30f;
    {
        const int m0 = 32 * h;
        float2 a0 = s_gt[(m0 + 127) & 127];
        float dax = a0.x - px, day = a0.y - py;
        float Da = fmaf(day, day, dax * dax);
        float fm = (float)(320 * h);
        #pragma unroll 4
        for (int j = 0; j < 32; ++j) {
            float4 S = s_seg[m0 + j];                 // wave-uniform broadcast
            float dgx = S.x - px, dgy = S.y - py;
            float Dg  = fmaf(dgy, dgy, dgx * dgx);
            float jv  = fmaf(Da - Dg, S.z, 5.0f);
            float jr  = rintf(__builtin_amdgcn_fmed3f(jv, 0.f, 9.f));
            float t   = fmaf(jv, -2.f, jr);           // jr - 2*jv
            float d   = fmaf(S.w * jr, t, Da);
            float fi  = fm + jr;
            if (d < b0) { b0 = d; f0 = fi; }          // ascending -> first occ.
            Da = Dg;
            fm += 10.f;
        }
    }
    s_rv[h * 64 + g] = b0;
    s_rf[h * 64 + g] = f0;
    __syncthreads();

    // merge 4 slices (64 active threads) + exact epilogue A
    if (tid < 64) {
        float best = s_rv[tid], bf = s_rf[tid];
        #pragma unroll
        for (int q = 1; q < 4; ++q) {
            float ov = s_rv[q * 64 + tid];
            float of = s_rf[q * 64 + tid];
            if (ov < best || (ov == best && of < bf)) { best = ov; bf = of; }
        }
        int bidx = (int)bf;
        int m = bidx / 10;
        int j = bidx - m * 10;
        float s  = s_step[j];
        float tt = 1.0f - s;
        float2 gm = s_gt[m];
        float2 gp = s_gt[(m + 127) & 127];
        float gx = gm.x * s + gp.x * tt;   // exact reference interp formula
        float gy = gm.y * s + gp.y * tt;
        float2 pr = s_pr[(half << 6) + tid];
        sumA = sl1(pr.x - gx) + sl1(pr.y - gy);
    }
    __syncthreads();   // protect s_rv/s_rf reuse

    // ---- Phase C: owned gt point vs ini slice [32h, 32h+32) ----
    {
        const float gx = myG.x, gy = myG.y;
        float b1 = INFINITY, f1 = 1e30f;
        float fk = (float)(32 * h);
        const int k0 = 32 * h;
        #pragma unroll 4
        for (int j = 0; j < 32; ++j) {
            float2 I = s_ii[k0 + j];                  // wave-uniform broadcast
            float dx = I.x - gx, dy = I.y - gy;
            float d  = fmaf(dy, dy, dx * dx);
            if (d < b1) { b1 = d; f1 = fk; }
            fk += 1.f;
        }
        s_rv[h * 64 + g] = b1;
        s_rf[h * 64 + g] = f1;
    }
    __syncthreads();

    if (tid < 64) {
        float best = s_rv[tid], bf = s_rf[tid];
        #pragma unroll
        for (int q = 1; q < 4; ++q) {
            float ov = s_rv[q * 64 + tid];
            float of = s_rf[q * 64 + tid];
            if (ov < best || (ov == best && of < bf)) { best = ov; bf = of; }
        }
        int k = (int)bf;
        float2 pk2 = s_pr[k];
        float2 g0  = s_gt[(half << 6) + tid];
        float  km  = kmask[b * MM + (half << 6) + tid];
        sumB = km * (sl1(pk2.x - g0.x) + sl1(pk2.y - g0.y));
        sumC = km;
    }

    // ---- Block reduction ----
    #pragma unroll
    for (int off = 32; off > 0; off >>= 1) {
        sumA += __shfl_down(sumA, off);
        sumB += __shfl_down(sumB, off);
        sumC += __shfl_down(sumC, off);
    }
    const int wave = tid >> 6;
    if ((tid & 63) == 0) {
        s_sum[0][wave] = sumA; s_sum[1][wave] = sumB; s_sum[2][wave] = sumC;
    }
    __syncthreads();
    if (tid == 0) {
        float A = 0.f, Bs = 0.f, C = 0.f;
        #pragma unroll
        for (int w = 0; w < 4; ++w) {
            A += s_sum[0][w]; Bs += s_sum[1][w]; C += s_sum[2][w];
        }
        partials[blockIdx.x] = make_float4(A, Bs, C, 0.0f);
    }
}

__global__ void __launch_bounds__(256)
dmloss_final(const float4* __restrict__ partials, float* __restrict__ out)
{
    const int tid = threadIdx.x;
    float A = 0.0f, Bs = 0.0f, C = 0.0f;
    #pragma unroll
    for (int i = tid; i < 2 * BB; i += 256) {
        float4 p = partials[i];
        A += p.x; Bs += p.y; C += p.z;
    }
    #pragma unroll
    for (int off = 32; off > 0; off >>= 1) {
        A  += __shfl_down(A, off);
        Bs += __shfl_down(Bs, off);
        C  += __shfl_down(C, off);
    }
    __shared__ float sA[4], sB[4], sC[4];
    const int wave = tid >> 6, lane = tid & 63;
    if (lane == 0) { sA[wave] = A; sB[wave] = Bs; sC[wave] = C; }
    __syncthreads();
    if (tid == 0) {
        float a  = sA[0] + sA[1] + sA[2] + sA[3];
        float bs = sB[0] + sB[1] + sB[2] + sB[3];
        float c  = sC[0] + sC[1] + sC[2] + sC[3];
        float loss_pred2gt = a / ((float)BB * (float)NN * 2.0f);
        float loss_set2set = bs / (2.0f * c + 1.0f) + loss_pred2gt;
        out[0] = 0.5f * loss_set2set;
    }
}

extern "C" void kernel_launch(void* const* d_in, const int* in_sizes, int n_in,
                              void* d_out, int out_size, void* d_ws, size_t ws_size,
                              hipStream_t stream)
{
    const float* ini   = (const float*)d_in[0];
    const float* pred  = (const float*)d_in[1];
    const float* gt    = (const float*)d_in[2];
    const float* kmask = (const float*)d_in[3];
    float4* partials = (float4*)d_ws;   // 2048 * 16 B = 32 KiB

    dmloss_main<<<dim3(2 * BB), dim3(256), 0, stream>>>(ini, pred, gt, kmask, partials);
    dmloss_final<<<dim3(1), dim3(256), 0, stream>>>(partials, (float*)d_out);
}